// Round 19
// baseline (78.804 us; speedup 1.0000x reference)
//
#include <hip/hip_runtime.h>

// SpectralConv2d via pruned partial DFTs (h-DFT first), 3-kernel fused pipeline.
// x: [16,32,256,256] f32 ; w1,w2: [32,32,12,12,2] f32 ; out: [16,32,256,256] f32
//  K12: per (bi, h-half) block: BARRIER-FREE radix-4 h-fold H-DFT. Thread = one w
//       column (scalar acc) -> no cross-wave reduce at all (r18 had 5 barrier
//       rounds + 27KB LDS round-trip); results go straight to Ys2, ONE barrier,
//       then quad-chain fused w-DFT -> partial Xf[half]. r18 named-var pipeline kept.
//  K3:  F[ky][kx][bo] = channel mix; sums the two Xf h-half partials; scale folded.
//  K45: per bo block: inverse ky-DFT -> G[bo] in LDS, then inverse w-DFT -> out
//       with NONTEMPORAL stores (r17: preserves x's L3 residency across replays).

#define TPI 6.28318530717958647692f

__global__ __launch_bounds__(256, 2) void k12_hwdft(const float* __restrict__ x,
                                                    float* __restrict__ Xf) {
  __shared__ float2 step2[64];      // (cos,sin)(2pi h'/256), h'=0..63 (0.5 KB)
  __shared__ float2 Ys2[13 * 260];  // [j][w] {C,S}, stride 260 (27 KB, f4-aligned)
  const int blk = blockIdx.x;       // 0..1023 = bi*2 + hf
  const int bi = blk >> 1, hf = blk & 1;
  const int t = threadIdx.x;        // t = w (0..255)

  if (t < 64) {
    float s, c;
    sincosf(TPI * (float)t * (1.0f / 256.0f), &s, &c);
    step2[t] = make_float2(c, s);
  }
  __syncthreads();

  const float* xp = x + (size_t)bi * 65536 + t;
  float aC[13], aS12[12];           // scalar acc; aS12[j-1] holds S_j (S_0 == 0)
#pragma unroll
  for (int j = 0; j < 13; j++) aC[j] = 0.0f;
#pragma unroll
  for (int j = 0; j < 12; j++) aS12[j] = 0.0f;

  const int h0 = hf * 32;
  // depth-1 named-var load pipeline (no arrays -> no spill surface)
  float c0 = xp[h0 * 256];
  float c1 = xp[(h0 + 64) * 256];
  float c2 = xp[(h0 + 128) * 256];
  float c3 = xp[(h0 + 192) * 256];
#pragma unroll 4
  for (int hh = 0; hh < 32; hh++) {
    int h = h0 + hh;                // h' in [h0, h0+32)
    int hn = h0 + ((hh + 1) & 31);  // next iter (wrap: harmless tail reload)
    float n0 = xp[hn * 256];
    float n1 = xp[(hn + 64) * 256];
    float n2 = xp[(hn + 128) * 256];
    float n3 = xp[(hn + 192) * 256];
    // radix-4 folds (algebra verified r15)
    float p02 = c0 + c2, m02 = c0 - c2;
    float p13 = c1 + c3, m13 = c1 - c3;
    float A = p02 + p13, Bv = p02 - p13;  // j%4==0 / j%4==2
    aC[0] += A;                     // j=0
    float2 st = step2[h];
    float cj = st.x, sj = st.y;     // phasor (cos j*th', sin j*th') at j=1
#pragma unroll
    for (int jj = 0; jj < 12; jj++) {
      const int j = jj + 1, r = j & 3;
      if (r == 0) {
        aC[j] = fmaf(A, cj, aC[j]);
        aS12[jj] = fmaf(A, sj, aS12[jj]);
      } else if (r == 2) {
        aC[j] = fmaf(Bv, cj, aC[j]);
        aS12[jj] = fmaf(Bv, sj, aS12[jj]);
      } else if (r == 1) {
        aC[j] = fmaf(m02, cj, fmaf(-m13, sj, aC[j]));
        aS12[jj] = fmaf(m02, sj, fmaf(m13, cj, aS12[jj]));
      } else {
        aC[j] = fmaf(m02, cj, fmaf(m13, sj, aC[j]));
        aS12[jj] = fmaf(m02, sj, fmaf(-m13, cj, aS12[jj]));
      }
      if (jj < 11) {
        float nc = fmaf(cj, st.x, -(sj * st.y));  // rotate by e^{i th'}
        float ns = fmaf(cj, st.y, sj * st.x);
        cj = nc; sj = ns;
      }
    }
    c0 = n0; c1 = n1; c2 = n2; c3 = n3;
  }

  // direct per-column write (no cross-wave reduce), one barrier
#pragma unroll
  for (int j = 0; j < 13; j++)
    Ys2[j * 260 + t] = make_float2(aC[j], (j == 0) ? 0.0f : aS12[j - 1]);
  __syncthreads();

  // fused w-DFT over full 256 w: quad phasor chains (ILP 4, 64 serial steps)
  if (t < 156) {
    int j = t / 12, kx = t % 12;    // j = |ky| 0..12
    float p1r, p1i, p2r, p2i, p3r, p3i, c4, s4;
    {
      float s, c;
      sincosf(TPI * (float)kx * (1.0f / 256.0f), &s, &c);          p1r = c; p1i = -s;
      sincosf(TPI * (float)((2 * kx) & 255) * (1.0f / 256.0f), &s, &c); p2r = c; p2i = -s;
      sincosf(TPI * (float)((3 * kx) & 255) * (1.0f / 256.0f), &s, &c); p3r = c; p3i = -s;
      sincosf(TPI * (float)((4 * kx) & 255) * (1.0f / 256.0f), &s, &c); c4 = c; s4 = -s;
    }
    const float2* CS = &Ys2[j * 260];
    float p0r = 1.0f, p0i = 0.0f;
    float A = 0, B = 0, D = 0, E = 0;
#pragma unroll 4
    for (int w = 0; w < 256; w += 4) {
      float4 v01 = *reinterpret_cast<const float4*>(&CS[w]);      // {C,S}w, {C,S}w+1
      float4 v23 = *reinterpret_cast<const float4*>(&CS[w + 2]);  // {C,S}w+2, {C,S}w+3
      A = fmaf(v01.x, p0r, A); B = fmaf(v01.x, p0i, B);
      D = fmaf(v01.y, p0r, D); E = fmaf(v01.y, p0i, E);
      A = fmaf(v01.z, p1r, A); B = fmaf(v01.z, p1i, B);
      D = fmaf(v01.w, p1r, D); E = fmaf(v01.w, p1i, E);
      A = fmaf(v23.x, p2r, A); B = fmaf(v23.x, p2i, B);
      D = fmaf(v23.y, p2r, D); E = fmaf(v23.y, p2i, E);
      A = fmaf(v23.z, p3r, A); B = fmaf(v23.z, p3i, B);
      D = fmaf(v23.w, p3r, D); E = fmaf(v23.w, p3i, E);
      float r0 = p0r * c4 - p0i * s4, i0 = p0r * s4 + p0i * c4;
      float r1 = p1r * c4 - p1i * s4, i1 = p1r * s4 + p1i * c4;
      float r2 = p2r * c4 - p2i * s4, i2 = p2r * s4 + p2i * c4;
      float r3 = p3r * c4 - p3i * s4, i3 = p3r * s4 + p3i * c4;
      p0r = r0; p0i = i0; p1r = r1; p1i = i1;
      p2r = r2; p2i = i2; p3r = r3; p3i = i3;
    }
    // X[ky=j] partial: re = A + E, im = B - D ; X[24-j]: re = A - E, im = B + D
    float2* Xo = reinterpret_cast<float2*>(Xf) + (size_t)hf * 147456;
    size_t base = (size_t)kx * 512 + bi;
    if (j <= 11) Xo[(size_t)j * 6144 + base] = make_float2(A + E, B - D);
    if (j >= 1)  Xo[(size_t)(24 - j) * 6144 + base] = make_float2(A - E, B + D);
  }
}

__global__ __launch_bounds__(256) void k3_mix(const float* __restrict__ Xf,
                                              const float* __restrict__ w1,
                                              const float* __restrict__ w2,
                                              float* __restrict__ Ff) {
  __shared__ float Xs[1024];  // [b][i][2]
  __shared__ float Ws[2048];  // [i][o][2]
  int m = blockIdx.x;         // ky*12 + kx, 288 blocks
  int ky = m / 12, kx = m % 12;
  int t = threadIdx.x;
  const float* Xsl = Xf + (size_t)m * 1024;
  for (int e = t; e < 1024; e += 256) Xs[e] = Xsl[e] + Xsl[e + 294912];  // sum halves
  const float* Wp = (ky < 12) ? w1 : w2;
  int myr = (ky < 12) ? ky : ky - 12;
  int woff = myr * 24 + kx * 2;
  for (int e = t; e < 1024; e += 256) {  // e = i*32 + o
    float2 wv = *reinterpret_cast<const float2*>(Wp + (size_t)e * 288 + woff);
    Ws[e * 2] = wv.x; Ws[e * 2 + 1] = wv.y;
  }
  __syncthreads();
  int o = t & 31, bh = t >> 5;  // bh 0..7 ; handles b = bh and bh+8
  float ar = 0, ai = 0, br = 0, bi_ = 0;
#pragma unroll
  for (int i = 0; i < 32; i++) {
    float wr = Ws[i * 64 + o * 2], wi = Ws[i * 64 + o * 2 + 1];
    float x1r = Xs[bh * 64 + i * 2], x1i = Xs[bh * 64 + i * 2 + 1];
    float x2r = Xs[(bh + 8) * 64 + i * 2], x2i = Xs[(bh + 8) * 64 + i * 2 + 1];
    ar = fmaf(x1r, wr, ar); ar = fmaf(-x1i, wi, ar);
    ai = fmaf(x1r, wi, ai); ai = fmaf(x1i, wr, ai);
    br = fmaf(x2r, wr, br); br = fmaf(-x2i, wi, br);
    bi_ = fmaf(x2r, wi, bi_); bi_ = fmaf(x2i, wr, bi_);
  }
  float scale = (kx == 0 ? 1.0f : 2.0f) * (1.0f / 65536.0f);
  float2* Fo = reinterpret_cast<float2*>(Ff) + (size_t)m * 512;
  Fo[(size_t)bh * 32 + o] = make_float2(ar * scale, ai * scale);
  Fo[(size_t)(bh + 8) * 32 + o] = make_float2(br * scale, bi_ * scale);
}

__global__ __launch_bounds__(256) void k45_inv(const float* __restrict__ Ff,
                                               float* __restrict__ out) {
  __shared__ float tw[128 * 27];     // [h][2j+{c,s}], pad 27 (13.8 KB)
  __shared__ float PQ[13 * 12 * 4];  // [j][kx][{Pr,Pi,Qr,Qi}] (2.4 KB)
  __shared__ float Gs[256 * 24];     // G[bo] rows (24.6 KB)
  const int bo = blockIdx.x;         // 0..511
  const int t = threadIdx.x;         // 0..255
  const int l = t & 63, wq = t >> 6;

  for (int e = t; e < 128 * 13; e += 256) {
    int h = e / 13, j = e % 13;
    float s, c;
    sincosf(TPI * (float)((h * j) & 255) * (1.0f / 256.0f), &s, &c);
    tw[h * 27 + 2 * j] = c;
    tw[h * 27 + 2 * j + 1] = s;
  }
  if (t < 156) {
    int j = t / 12, kx = t % 12;
    const float2* F2 = reinterpret_cast<const float2*>(Ff);
    float lr = 0, li = 0, hr = 0, hi = 0;
    if (j < 12) { float2 v = F2[((size_t)j * 12 + kx) * 512 + bo]; lr = v.x; li = v.y; }
    if (j > 0)  { float2 v = F2[((size_t)(24 - j) * 12 + kx) * 512 + bo]; hr = v.x; hi = v.y; }
    PQ[(j * 12 + kx) * 4 + 0] = lr + hr;  // Pr
    PQ[(j * 12 + kx) * 4 + 1] = li + hi;  // Pi
    PQ[(j * 12 + kx) * 4 + 2] = hi - li;  // Qr
    PQ[(j * 12 + kx) * 4 + 3] = lr - hr;  // Qi
  }
  __syncthreads();

  // Phase A: inverse ky-DFT -> Gs (t < 192: 16 hq x 12 kx)
  if (t < 192) {
    const int kx = t % 12, hq = t / 12;  // hq 0..15
    float Pr[13], Pi[13], Qr[13], Qi[13];
#pragma unroll
    for (int j = 0; j < 13; j++) {
      Pr[j] = PQ[(j * 12 + kx) * 4 + 0];
      Pi[j] = PQ[(j * 12 + kx) * 4 + 1];
      Qr[j] = PQ[(j * 12 + kx) * 4 + 2];
      Qi[j] = PQ[(j * 12 + kx) * 4 + 3];
    }
    for (int hh = 0; hh < 8; hh++) {
      int h = hh * 16 + hq;  // 0..127
      float Er = 0, Ei = 0, Or = 0, Oi = 0;
#pragma unroll
      for (int j = 0; j < 13; j++) {
        float c = tw[h * 27 + 2 * j], s = tw[h * 27 + 2 * j + 1];
        if (j & 1) {
          Or = fmaf(Pr[j], c, Or); Or = fmaf(Qr[j], s, Or);
          Oi = fmaf(Pi[j], c, Oi); Oi = fmaf(Qi[j], s, Oi);
        } else {
          Er = fmaf(Pr[j], c, Er); Er = fmaf(Qr[j], s, Er);
          Ei = fmaf(Pi[j], c, Ei); Ei = fmaf(Qi[j], s, Ei);
        }
      }
      Gs[h * 24 + 2 * kx] = Er + Or;           // G[h]
      Gs[h * 24 + 2 * kx + 1] = Ei + Oi;
      Gs[(h + 128) * 24 + 2 * kx] = Er - Or;   // G[h+128]
      Gs[(h + 128) * 24 + 2 * kx + 1] = Ei - Oi;
    }
  }

  // Phase B twiddles (independent of Gs -> before barrier)
  float cA[12], sA[12], cB[12], sB[12];
#pragma unroll
  for (int kx = 1; kx < 12; kx++) {
    float s, c;
    __sincosf(TPI * (float)((kx * (2 * l)) & 255) * (1.0f / 256.0f), &s, &c);
    cA[kx] = c; sA[kx] = s;
    __sincosf(TPI * (float)((kx * (2 * l + 1)) & 255) * (1.0f / 256.0f), &s, &c);
    cB[kx] = c; sB[kx] = s;
  }
  __syncthreads();

  // Phase B: inverse w-DFT from Gs; NONTEMPORAL stores (don't evict x from L3)
  float* ob0 = out + ((size_t)bo * 256 + wq * 64) * 256;
  for (int rs = 0; rs < 64; rs++) {
    int rl = wq * 64 + rs;
    float g[24];
    const float4* gr4 = reinterpret_cast<const float4*>(&Gs[rl * 24]);
#pragma unroll
    for (int qq = 0; qq < 6; qq++) {
      float4 v = gr4[qq];
      g[4 * qq] = v.x; g[4 * qq + 1] = v.y; g[4 * qq + 2] = v.z; g[4 * qq + 3] = v.w;
    }
    float E0 = g[0], O0 = 0, E1 = g[0], O1 = 0;  // DC: Re(G0) only
#pragma unroll
    for (int kx = 1; kx < 12; kx++) {
      float ta = g[2 * kx] * cA[kx] - g[2 * kx + 1] * sA[kx];
      float tb = g[2 * kx] * cB[kx] - g[2 * kx + 1] * sB[kx];
      if (kx & 1) { O0 += ta; O1 += tb; } else { E0 += ta; E1 += tb; }
    }
    float* orow = ob0 + rs * 256;
    float2 v0 = make_float2(E0 + O0, E1 + O1);
    float2 v1 = make_float2(E0 - O0, E1 - O1);
    __builtin_nontemporal_store(*reinterpret_cast<double*>(&v0),
                                reinterpret_cast<double*>(&orow[2 * l]));
    __builtin_nontemporal_store(*reinterpret_cast<double*>(&v1),
                                reinterpret_cast<double*>(&orow[128 + 2 * l]));
  }
}

extern "C" void kernel_launch(void* const* d_in, const int* in_sizes, int n_in,
                              void* d_out, int out_size, void* d_ws, size_t ws_size,
                              hipStream_t stream) {
  const float* x = (const float*)d_in[0];
  const float* w1 = (const float*)d_in[1];
  const float* w2 = (const float*)d_in[2];
  float* out = (float*)d_out;
  float* ws = (float*)d_ws;

  float* Xf = ws;               // 2 x 294,912 floats (partial h-halves)
  float* Ff = ws + 589824;      //     294,912 floats

  k12_hwdft<<<1024, 256, 0, stream>>>(x, Xf);
  k3_mix<<<288, 256, 0, stream>>>(Xf, w1, w2, Ff);
  k45_inv<<<512, 256, 0, stream>>>(Ff, out);
}

// Round 20
// 77.168 us; speedup vs baseline: 1.0212x; 1.0212x over previous
//
#include <hip/hip_runtime.h>

// SpectralConv2d via pruned partial DFTs (h-DFT first), 2-kernel fused pipeline.
// x: [16,32,256,256] f32 ; w1,w2: [32,32,12,12,2] f32 ; out: [16,32,256,256] f32
//  K12: per (bi, w-half) block: radix-4 h-fold H-DFT (r15/r17/r18 base: named-var
//       depth-1 load pipeline, unroll 4, 2-pass reduce, dual-chain epilogue).
//  K45: per bo block: FUSED channel mix (r20: k3 folded into prologue — Xf and W are
//       L2/L3-resident, 288x 32-term dots ≈ 74k FLOP/block) -> Fs in LDS -> PQ ->
//       inverse ky-DFT -> Gs -> inverse w-DFT -> out with NONTEMPORAL stores
//       (r17: preserves x's L3 residency across graph replays).

#define TPI 6.28318530717958647692f

__global__ __launch_bounds__(256, 2) void k12_hwdft(const float* __restrict__ x,
                                                    float* __restrict__ Xf) {
  __shared__ float2 step2[64];         // (cos,sin)(2pi h'/256), h'=0..63 (0.5 KB)
  __shared__ float red[4 * 13 * 128];  // cross-wave reduce, 2 passes (26.6 KB)
  __shared__ float2 Ys2[13 * 130];     // [j][w-local] {C,S}, stride 130 (13.5 KB)
  const int blk = blockIdx.x;          // 0..1023 = bi*2 + wh
  const int bi = blk >> 1, wh = blk & 1;
  const int t = threadIdx.x;
  const int q = t >> 6, l = t & 63;    // wave q -> 16 h'-groups, lane l -> 2 w's

  if (t < 64) {
    float s, c;
    sincosf(TPI * (float)t * (1.0f / 256.0f), &s, &c);
    step2[t] = make_float2(c, s);
  }
  __syncthreads();

  const float2* xp2 = reinterpret_cast<const float2*>(x + (size_t)bi * 65536 + wh * 128) + l;
  float2 aC[13], aS12[12];             // aS12[j-1] holds S_j (S_0 == 0)
#pragma unroll
  for (int j = 0; j < 13; j++) aC[j] = make_float2(0.f, 0.f);
#pragma unroll
  for (int j = 0; j < 12; j++) aS12[j] = make_float2(0.f, 0.f);

  const int h0 = q * 16;
  // depth-1 software pipeline: named vars only (no arrays -> no spill surface)
  float2 c0 = xp2[h0 * 128];
  float2 c1 = xp2[(h0 + 64) * 128];
  float2 c2 = xp2[(h0 + 128) * 128];
  float2 c3 = xp2[(h0 + 192) * 128];
#pragma unroll 4
  for (int hh = 0; hh < 16; hh++) {
    int h = h0 + hh;                   // h' in [0,64)
    int hn = h0 + ((hh + 1) & 15);     // next iter (wrap: harmless reload at tail)
    float2 n0 = xp2[hn * 128];
    float2 n1 = xp2[(hn + 64) * 128];
    float2 n2 = xp2[(hn + 128) * 128];
    float2 n3 = xp2[(hn + 192) * 128];
    float2 p02 = make_float2(c0.x + c2.x, c0.y + c2.y);
    float2 m02 = make_float2(c0.x - c2.x, c0.y - c2.y);
    float2 p13 = make_float2(c1.x + c3.x, c1.y + c3.y);
    float2 m13 = make_float2(c1.x - c3.x, c1.y - c3.y);
    float2 A = make_float2(p02.x + p13.x, p02.y + p13.y);   // j % 4 == 0
    float2 Bv = make_float2(p02.x - p13.x, p02.y - p13.y);  // j % 4 == 2
    aC[0].x += A.x; aC[0].y += A.y;    // j=0
    float2 st = step2[h];
    float cj = st.x, sj = st.y;        // phasor at j=1
#pragma unroll
    for (int jj = 0; jj < 12; jj++) {
      const int j = jj + 1, r = j & 3;
      if (r == 0) {
        aC[j].x = fmaf(A.x, cj, aC[j].x);   aC[j].y = fmaf(A.y, cj, aC[j].y);
        aS12[jj].x = fmaf(A.x, sj, aS12[jj].x); aS12[jj].y = fmaf(A.y, sj, aS12[jj].y);
      } else if (r == 2) {
        aC[j].x = fmaf(Bv.x, cj, aC[j].x);  aC[j].y = fmaf(Bv.y, cj, aC[j].y);
        aS12[jj].x = fmaf(Bv.x, sj, aS12[jj].x); aS12[jj].y = fmaf(Bv.y, sj, aS12[jj].y);
      } else if (r == 1) {
        aC[j].x = fmaf(m02.x, cj, fmaf(-m13.x, sj, aC[j].x));
        aC[j].y = fmaf(m02.y, cj, fmaf(-m13.y, sj, aC[j].y));
        aS12[jj].x = fmaf(m02.x, sj, fmaf(m13.x, cj, aS12[jj].x));
        aS12[jj].y = fmaf(m02.y, sj, fmaf(m13.y, cj, aS12[jj].y));
      } else {
        aC[j].x = fmaf(m02.x, cj, fmaf(m13.x, sj, aC[j].x));
        aC[j].y = fmaf(m02.y, cj, fmaf(m13.y, sj, aC[j].y));
        aS12[jj].x = fmaf(m02.x, sj, fmaf(-m13.x, cj, aS12[jj].x));
        aS12[jj].y = fmaf(m02.y, sj, fmaf(-m13.y, cj, aS12[jj].y));
      }
      if (jj < 11) {
        float nc = fmaf(cj, st.x, -(sj * st.y));  // rotate by e^{i th'}
        float ns = fmaf(cj, st.y, sj * st.x);
        cj = nc; sj = ns;
      }
    }
    c0 = n0; c1 = n1; c2 = n2; c3 = n3;
  }

  // cross-wave reduce into Ys2: 2 passes x 13 classes (cls = 2j: C_j, 2j+1: S_j)
  for (int p = 0; p < 2; p++) {
    __syncthreads();
#pragma unroll
    for (int cc = 0; cc < 13; cc++) {
      int cls = p * 13 + cc;
      int j = cls >> 1;
      float2 v;
      if (cls & 1) v = (j == 0) ? make_float2(0.f, 0.f) : aS12[j - 1];
      else v = aC[j];
      *reinterpret_cast<float2*>(&red[(q * 13 + cc) * 128 + 2 * l]) = v;
    }
    __syncthreads();
    for (int idx = t; idx < 13 * 128; idx += 256) {
      int cc = idx >> 7, wl = idx & 127;
      int cls = p * 13 + cc;
      float s = red[(0 * 13 + cc) * 128 + wl] + red[(1 * 13 + cc) * 128 + wl] +
                red[(2 * 13 + cc) * 128 + wl] + red[(3 * 13 + cc) * 128 + wl];
      if (cls & 1) Ys2[(cls >> 1) * 130 + wl].y = s;
      else         Ys2[(cls >> 1) * 130 + wl].x = s;
    }
  }
  __syncthreads();

  // fused w-DFT: dual even/odd-w phasor chains (ILP 2, serial chain 64 steps)
  if (t < 156) {
    int j = t / 12, kx = t % 12;  // j = |ky| 0..12
    float c1p, s1p, c2p, s2p;
    {
      float s, c;
      sincosf(TPI * (float)kx * (1.0f / 256.0f), &s, &c);
      c1p = c; s1p = -s;                     // odd-chain start phasor (w=1)
      sincosf(TPI * (float)((2 * kx) & 255) * (1.0f / 256.0f), &s, &c);
      c2p = c; s2p = -s;                     // both chains step e^{-i 2 kx th}
    }
    const float2* CS = &Ys2[j * 130];
    float pr0 = 1.0f, pi0 = 0.0f;            // even chain (w=0,2,..)
    float pr1 = c1p, pi1 = s1p;              // odd chain  (w=1,3,..)
    float A = 0, B = 0, D = 0, E = 0;
#pragma unroll 4
    for (int w = 0; w < 128; w += 2) {
      float4 vv = *reinterpret_cast<const float4*>(&CS[w]);  // {C_w,S_w,C_w+1,S_w+1}
      A = fmaf(vv.x, pr0, A); B = fmaf(vv.x, pi0, B);
      D = fmaf(vv.y, pr0, D); E = fmaf(vv.y, pi0, E);
      A = fmaf(vv.z, pr1, A); B = fmaf(vv.z, pi1, B);
      D = fmaf(vv.w, pr1, D); E = fmaf(vv.w, pi1, E);
      float n0r = pr0 * c2p - pi0 * s2p, n0i = pr0 * s2p + pi0 * c2p;
      float n1r = pr1 * c2p - pi1 * s2p, n1i = pr1 * s2p + pi1 * c2p;
      pr0 = n0r; pi0 = n0i; pr1 = n1r; pi1 = n1i;
    }
    // global w = wh*128 + w'  ->  multiply by (-1)^(kx*wh)
    float sgn = (wh && (kx & 1)) ? -1.0f : 1.0f;
    A *= sgn; B *= sgn; D *= sgn; E *= sgn;
    float2* Xo = reinterpret_cast<float2*>(Xf) + (size_t)wh * 147456;
    size_t base = (size_t)kx * 512 + bi;
    if (j <= 11) Xo[(size_t)j * 6144 + base] = make_float2(A + E, B - D);
    if (j >= 1)  Xo[(size_t)(24 - j) * 6144 + base] = make_float2(A - E, B + D);
  }
}

__global__ __launch_bounds__(256) void k45_inv(const float* __restrict__ Xf,
                                               const float* __restrict__ w1,
                                               const float* __restrict__ w2,
                                               float* __restrict__ out) {
  __shared__ float tw[128 * 27];     // [h][2j+{c,s}], pad 27 (13.8 KB)
  __shared__ float2 Fs[288];         // fused-mix result for this bo (2.3 KB)
  __shared__ float PQ[13 * 12 * 4];  // [j][kx][{Pr,Pi,Qr,Qi}] (2.4 KB)
  __shared__ float Gs[256 * 24];     // G[bo] rows (24.6 KB)
  const int bo = blockIdx.x;         // 0..511
  const int t = threadIdx.x;         // 0..255
  const int l = t & 63, wq = t >> 6;
  const int b = bo >> 5, o = bo & 31;

  for (int e = t; e < 128 * 13; e += 256) {
    int h = e / 13, j = e % 13;
    float s, c;
    sincosf(TPI * (float)((h * j) & 255) * (1.0f / 256.0f), &s, &c);
    tw[h * 27 + 2 * j] = c;
    tw[h * 27 + 2 * j + 1] = s;
  }

  // fused k3: F[m] for this bo = sum_i (X_half0+X_half1)[m][b*32+i] * W[i][o][m]
  for (int m = t; m < 288; m += 256) {
    int ky = m / 12, kx = m % 12;
    const float* Wp = (ky < 12) ? w1 : w2;
    int myr = (ky < 12) ? ky : ky - 12;
    int woff = myr * 24 + kx * 2;
    const float2* Xm = reinterpret_cast<const float2*>(Xf) + (size_t)m * 512 + b * 32;
    float ar = 0, ai = 0;
#pragma unroll 8
    for (int i = 0; i < 32; i++) {
      float2 x0 = Xm[i];
      float2 x1 = Xm[i + 147456];     // second w-half partial
      float xr = x0.x + x1.x, xi = x0.y + x1.y;
      float2 wv = *reinterpret_cast<const float2*>(Wp + ((size_t)i * 32 + o) * 288 + woff);
      ar = fmaf(xr, wv.x, fmaf(-xi, wv.y, ar));
      ai = fmaf(xr, wv.y, fmaf(xi, wv.x, ai));
    }
    float scale = (kx == 0 ? 1.0f : 2.0f) * (1.0f / 65536.0f);
    Fs[m] = make_float2(ar * scale, ai * scale);
  }
  __syncthreads();

  if (t < 156) {
    int j = t / 12, kx = t % 12;
    float lr = 0, li = 0, hr = 0, hi = 0;
    if (j < 12) { float2 v = Fs[j * 12 + kx]; lr = v.x; li = v.y; }
    if (j > 0)  { float2 v = Fs[(24 - j) * 12 + kx]; hr = v.x; hi = v.y; }
    PQ[(j * 12 + kx) * 4 + 0] = lr + hr;  // Pr
    PQ[(j * 12 + kx) * 4 + 1] = li + hi;  // Pi
    PQ[(j * 12 + kx) * 4 + 2] = hi - li;  // Qr
    PQ[(j * 12 + kx) * 4 + 3] = lr - hr;  // Qi
  }
  __syncthreads();

  // Phase A: inverse ky-DFT -> Gs (t < 192: 16 hq x 12 kx)
  if (t < 192) {
    const int kx = t % 12, hq = t / 12;  // hq 0..15
    float Pr[13], Pi[13], Qr[13], Qi[13];
#pragma unroll
    for (int j = 0; j < 13; j++) {
      Pr[j] = PQ[(j * 12 + kx) * 4 + 0];
      Pi[j] = PQ[(j * 12 + kx) * 4 + 1];
      Qr[j] = PQ[(j * 12 + kx) * 4 + 2];
      Qi[j] = PQ[(j * 12 + kx) * 4 + 3];
    }
    for (int hh = 0; hh < 8; hh++) {
      int h = hh * 16 + hq;  // 0..127
      float Er = 0, Ei = 0, Or = 0, Oi = 0;
#pragma unroll
      for (int j = 0; j < 13; j++) {
        float c = tw[h * 27 + 2 * j], s = tw[h * 27 + 2 * j + 1];
        if (j & 1) {
          Or = fmaf(Pr[j], c, Or); Or = fmaf(Qr[j], s, Or);
          Oi = fmaf(Pi[j], c, Oi); Oi = fmaf(Qi[j], s, Oi);
        } else {
          Er = fmaf(Pr[j], c, Er); Er = fmaf(Qr[j], s, Er);
          Ei = fmaf(Pi[j], c, Ei); Ei = fmaf(Qi[j], s, Ei);
        }
      }
      Gs[h * 24 + 2 * kx] = Er + Or;           // G[h]
      Gs[h * 24 + 2 * kx + 1] = Ei + Oi;
      Gs[(h + 128) * 24 + 2 * kx] = Er - Or;   // G[h+128]
      Gs[(h + 128) * 24 + 2 * kx + 1] = Ei - Oi;
    }
  }

  // Phase B twiddles (independent of Gs -> before barrier)
  float cA[12], sA[12], cB[12], sB[12];
#pragma unroll
  for (int kx = 1; kx < 12; kx++) {
    float s, c;
    __sincosf(TPI * (float)((kx * (2 * l)) & 255) * (1.0f / 256.0f), &s, &c);
    cA[kx] = c; sA[kx] = s;
    __sincosf(TPI * (float)((kx * (2 * l + 1)) & 255) * (1.0f / 256.0f), &s, &c);
    cB[kx] = c; sB[kx] = s;
  }
  __syncthreads();

  // Phase B: inverse w-DFT from Gs; NONTEMPORAL stores (don't evict x from L3)
  float* ob0 = out + ((size_t)bo * 256 + wq * 64) * 256;
  for (int rs = 0; rs < 64; rs++) {
    int rl = wq * 64 + rs;
    float g[24];
    const float4* gr4 = reinterpret_cast<const float4*>(&Gs[rl * 24]);
#pragma unroll
    for (int qq = 0; qq < 6; qq++) {
      float4 v = gr4[qq];
      g[4 * qq] = v.x; g[4 * qq + 1] = v.y; g[4 * qq + 2] = v.z; g[4 * qq + 3] = v.w;
    }
    float E0 = g[0], O0 = 0, E1 = g[0], O1 = 0;  // DC: Re(G0) only
#pragma unroll
    for (int kx = 1; kx < 12; kx++) {
      float ta = g[2 * kx] * cA[kx] - g[2 * kx + 1] * sA[kx];
      float tb = g[2 * kx] * cB[kx] - g[2 * kx + 1] * sB[kx];
      if (kx & 1) { O0 += ta; O1 += tb; } else { E0 += ta; E1 += tb; }
    }
    float* orow = ob0 + rs * 256;
    float2 v0 = make_float2(E0 + O0, E1 + O1);
    float2 v1 = make_float2(E0 - O0, E1 - O1);
    __builtin_nontemporal_store(*reinterpret_cast<double*>(&v0),
                                reinterpret_cast<double*>(&orow[2 * l]));
    __builtin_nontemporal_store(*reinterpret_cast<double*>(&v1),
                                reinterpret_cast<double*>(&orow[128 + 2 * l]));
  }
}

extern "C" void kernel_launch(void* const* d_in, const int* in_sizes, int n_in,
                              void* d_out, int out_size, void* d_ws, size_t ws_size,
                              hipStream_t stream) {
  const float* x = (const float*)d_in[0];
  const float* w1 = (const float*)d_in[1];
  const float* w2 = (const float*)d_in[2];
  float* out = (float*)d_out;
  float* ws = (float*)d_ws;

  float* Xf = ws;  // 2 x 294,912 floats (partial w-halves)

  k12_hwdft<<<1024, 256, 0, stream>>>(x, Xf);
  k45_inv<<<512, 256, 0, stream>>>(Xf, w1, w2, out);
}

// Round 21
// 73.069 us; speedup vs baseline: 1.0785x; 1.0561x over previous
//
#include <hip/hip_runtime.h>

// SpectralConv2d via pruned partial DFTs (h-DFT first), 3-kernel fused pipeline.
// x: [16,32,256,256] f32 ; w1,w2: [32,32,12,12,2] f32 ; out: [16,32,256,256] f32
// REVERT to r18 best (73.17us): r19 (barrier-free k12) and r20 (k3 fused into k45)
// both regressed. Ledger: k12 wins = radix-4 fold, Y-roundtrip fusion, nt-stores,
// 2-pass reduce, dual-chain epilogue, named-var load pipeline.
//  K12: per (bi, w-half) block: radix-4 h-fold H-DFT, depth-1 named-var load
//       pipeline + unroll 4; 2-pass cross-wave reduce; dual-chain fused w-DFT.
//  K3:  F[ky][kx][bo] = channel mix; sums the two Xf halves; scale folded in.
//  K45: per bo block: inverse ky-DFT -> G[bo] in LDS, then inverse w-DFT -> out
//       with NONTEMPORAL stores (preserves x's L3 residency across replays).

#define TPI 6.28318530717958647692f

__global__ __launch_bounds__(256, 2) void k12_hwdft(const float* __restrict__ x,
                                                    float* __restrict__ Xf) {
  __shared__ float2 step2[64];         // (cos,sin)(2pi h'/256), h'=0..63 (0.5 KB)
  __shared__ float red[4 * 13 * 128];  // cross-wave reduce, 2 passes (26.6 KB)
  __shared__ float2 Ys2[13 * 130];     // [j][w-local] {C,S}, stride 130 (13.5 KB)
  const int blk = blockIdx.x;          // 0..1023 = bi*2 + wh
  const int bi = blk >> 1, wh = blk & 1;
  const int t = threadIdx.x;
  const int q = t >> 6, l = t & 63;    // wave q -> 16 h'-groups, lane l -> 2 w's

  if (t < 64) {
    float s, c;
    sincosf(TPI * (float)t * (1.0f / 256.0f), &s, &c);
    step2[t] = make_float2(c, s);
  }
  __syncthreads();

  const float2* xp2 = reinterpret_cast<const float2*>(x + (size_t)bi * 65536 + wh * 128) + l;
  float2 aC[13], aS12[12];             // aS12[j-1] holds S_j (S_0 == 0)
#pragma unroll
  for (int j = 0; j < 13; j++) aC[j] = make_float2(0.f, 0.f);
#pragma unroll
  for (int j = 0; j < 12; j++) aS12[j] = make_float2(0.f, 0.f);

  const int h0 = q * 16;
  // depth-1 software pipeline: named vars only (no arrays -> no spill surface)
  float2 c0 = xp2[h0 * 128];
  float2 c1 = xp2[(h0 + 64) * 128];
  float2 c2 = xp2[(h0 + 128) * 128];
  float2 c3 = xp2[(h0 + 192) * 128];
#pragma unroll 4
  for (int hh = 0; hh < 16; hh++) {
    int h = h0 + hh;                   // h' in [0,64)
    int hn = h0 + ((hh + 1) & 15);     // next iter (wrap: harmless reload at tail)
    float2 n0 = xp2[hn * 128];
    float2 n1 = xp2[(hn + 64) * 128];
    float2 n2 = xp2[(hn + 128) * 128];
    float2 n3 = xp2[(hn + 192) * 128];
    float2 p02 = make_float2(c0.x + c2.x, c0.y + c2.y);
    float2 m02 = make_float2(c0.x - c2.x, c0.y - c2.y);
    float2 p13 = make_float2(c1.x + c3.x, c1.y + c3.y);
    float2 m13 = make_float2(c1.x - c3.x, c1.y - c3.y);
    float2 A = make_float2(p02.x + p13.x, p02.y + p13.y);   // j % 4 == 0
    float2 Bv = make_float2(p02.x - p13.x, p02.y - p13.y);  // j % 4 == 2
    aC[0].x += A.x; aC[0].y += A.y;    // j=0
    float2 st = step2[h];
    float cj = st.x, sj = st.y;        // phasor at j=1
#pragma unroll
    for (int jj = 0; jj < 12; jj++) {
      const int j = jj + 1, r = j & 3;
      if (r == 0) {
        aC[j].x = fmaf(A.x, cj, aC[j].x);   aC[j].y = fmaf(A.y, cj, aC[j].y);
        aS12[jj].x = fmaf(A.x, sj, aS12[jj].x); aS12[jj].y = fmaf(A.y, sj, aS12[jj].y);
      } else if (r == 2) {
        aC[j].x = fmaf(Bv.x, cj, aC[j].x);  aC[j].y = fmaf(Bv.y, cj, aC[j].y);
        aS12[jj].x = fmaf(Bv.x, sj, aS12[jj].x); aS12[jj].y = fmaf(Bv.y, sj, aS12[jj].y);
      } else if (r == 1) {
        aC[j].x = fmaf(m02.x, cj, fmaf(-m13.x, sj, aC[j].x));
        aC[j].y = fmaf(m02.y, cj, fmaf(-m13.y, sj, aC[j].y));
        aS12[jj].x = fmaf(m02.x, sj, fmaf(m13.x, cj, aS12[jj].x));
        aS12[jj].y = fmaf(m02.y, sj, fmaf(m13.y, cj, aS12[jj].y));
      } else {
        aC[j].x = fmaf(m02.x, cj, fmaf(m13.x, sj, aC[j].x));
        aC[j].y = fmaf(m02.y, cj, fmaf(m13.y, sj, aC[j].y));
        aS12[jj].x = fmaf(m02.x, sj, fmaf(-m13.x, cj, aS12[jj].x));
        aS12[jj].y = fmaf(m02.y, sj, fmaf(-m13.y, cj, aS12[jj].y));
      }
      if (jj < 11) {
        float nc = fmaf(cj, st.x, -(sj * st.y));  // rotate by e^{i th'}
        float ns = fmaf(cj, st.y, sj * st.x);
        cj = nc; sj = ns;
      }
    }
    c0 = n0; c1 = n1; c2 = n2; c3 = n3;
  }

  // cross-wave reduce into Ys2: 2 passes x 13 classes (cls = 2j: C_j, 2j+1: S_j)
  for (int p = 0; p < 2; p++) {
    __syncthreads();
#pragma unroll
    for (int cc = 0; cc < 13; cc++) {
      int cls = p * 13 + cc;
      int j = cls >> 1;
      float2 v;
      if (cls & 1) v = (j == 0) ? make_float2(0.f, 0.f) : aS12[j - 1];
      else v = aC[j];
      *reinterpret_cast<float2*>(&red[(q * 13 + cc) * 128 + 2 * l]) = v;
    }
    __syncthreads();
    for (int idx = t; idx < 13 * 128; idx += 256) {
      int cc = idx >> 7, wl = idx & 127;
      int cls = p * 13 + cc;
      float s = red[(0 * 13 + cc) * 128 + wl] + red[(1 * 13 + cc) * 128 + wl] +
                red[(2 * 13 + cc) * 128 + wl] + red[(3 * 13 + cc) * 128 + wl];
      if (cls & 1) Ys2[(cls >> 1) * 130 + wl].y = s;
      else         Ys2[(cls >> 1) * 130 + wl].x = s;
    }
  }
  __syncthreads();

  // fused w-DFT: dual even/odd-w phasor chains (ILP 2, serial chain 64 steps)
  if (t < 156) {
    int j = t / 12, kx = t % 12;  // j = |ky| 0..12
    float c1p, s1p, c2p, s2p;
    {
      float s, c;
      sincosf(TPI * (float)kx * (1.0f / 256.0f), &s, &c);
      c1p = c; s1p = -s;                     // odd-chain start phasor (w=1)
      sincosf(TPI * (float)((2 * kx) & 255) * (1.0f / 256.0f), &s, &c);
      c2p = c; s2p = -s;                     // both chains step e^{-i 2 kx th}
    }
    const float2* CS = &Ys2[j * 130];
    float pr0 = 1.0f, pi0 = 0.0f;            // even chain (w=0,2,..)
    float pr1 = c1p, pi1 = s1p;              // odd chain  (w=1,3,..)
    float A = 0, B = 0, D = 0, E = 0;
#pragma unroll 4
    for (int w = 0; w < 128; w += 2) {
      float4 vv = *reinterpret_cast<const float4*>(&CS[w]);  // {C_w,S_w,C_w+1,S_w+1}
      A = fmaf(vv.x, pr0, A); B = fmaf(vv.x, pi0, B);
      D = fmaf(vv.y, pr0, D); E = fmaf(vv.y, pi0, E);
      A = fmaf(vv.z, pr1, A); B = fmaf(vv.z, pi1, B);
      D = fmaf(vv.w, pr1, D); E = fmaf(vv.w, pi1, E);
      float n0r = pr0 * c2p - pi0 * s2p, n0i = pr0 * s2p + pi0 * c2p;
      float n1r = pr1 * c2p - pi1 * s2p, n1i = pr1 * s2p + pi1 * c2p;
      pr0 = n0r; pi0 = n0i; pr1 = n1r; pi1 = n1i;
    }
    // global w = wh*128 + w'  ->  multiply by (-1)^(kx*wh)
    float sgn = (wh && (kx & 1)) ? -1.0f : 1.0f;
    A *= sgn; B *= sgn; D *= sgn; E *= sgn;
    float2* Xo = reinterpret_cast<float2*>(Xf) + (size_t)wh * 147456;
    size_t base = (size_t)kx * 512 + bi;
    if (j <= 11) Xo[(size_t)j * 6144 + base] = make_float2(A + E, B - D);
    if (j >= 1)  Xo[(size_t)(24 - j) * 6144 + base] = make_float2(A - E, B + D);
  }
}

__global__ __launch_bounds__(256) void k3_mix(const float* __restrict__ Xf,
                                              const float* __restrict__ w1,
                                              const float* __restrict__ w2,
                                              float* __restrict__ Ff) {
  __shared__ float Xs[1024];  // [b][i][2]
  __shared__ float Ws[2048];  // [i][o][2]
  int m = blockIdx.x;         // ky*12 + kx, 288 blocks
  int ky = m / 12, kx = m % 12;
  int t = threadIdx.x;
  const float* Xsl = Xf + (size_t)m * 1024;
  for (int e = t; e < 1024; e += 256) Xs[e] = Xsl[e] + Xsl[e + 294912];  // sum halves
  const float* Wp = (ky < 12) ? w1 : w2;
  int myr = (ky < 12) ? ky : ky - 12;
  int woff = myr * 24 + kx * 2;
  for (int e = t; e < 1024; e += 256) {  // e = i*32 + o
    float2 wv = *reinterpret_cast<const float2*>(Wp + (size_t)e * 288 + woff);
    Ws[e * 2] = wv.x; Ws[e * 2 + 1] = wv.y;
  }
  __syncthreads();
  int o = t & 31, bh = t >> 5;  // bh 0..7 ; handles b = bh and bh+8
  float ar = 0, ai = 0, br = 0, bi_ = 0;
#pragma unroll
  for (int i = 0; i < 32; i++) {
    float wr = Ws[i * 64 + o * 2], wi = Ws[i * 64 + o * 2 + 1];
    float x1r = Xs[bh * 64 + i * 2], x1i = Xs[bh * 64 + i * 2 + 1];
    float x2r = Xs[(bh + 8) * 64 + i * 2], x2i = Xs[(bh + 8) * 64 + i * 2 + 1];
    ar = fmaf(x1r, wr, ar); ar = fmaf(-x1i, wi, ar);
    ai = fmaf(x1r, wi, ai); ai = fmaf(x1i, wr, ai);
    br = fmaf(x2r, wr, br); br = fmaf(-x2i, wi, br);
    bi_ = fmaf(x2r, wi, bi_); bi_ = fmaf(x2i, wr, bi_);
  }
  float scale = (kx == 0 ? 1.0f : 2.0f) * (1.0f / 65536.0f);
  float2* Fo = reinterpret_cast<float2*>(Ff) + (size_t)m * 512;
  Fo[(size_t)bh * 32 + o] = make_float2(ar * scale, ai * scale);
  Fo[(size_t)(bh + 8) * 32 + o] = make_float2(br * scale, bi_ * scale);
}

__global__ __launch_bounds__(256) void k45_inv(const float* __restrict__ Ff,
                                               float* __restrict__ out) {
  __shared__ float tw[128 * 27];     // [h][2j+{c,s}], pad 27 (13.8 KB)
  __shared__ float PQ[13 * 12 * 4];  // [j][kx][{Pr,Pi,Qr,Qi}] (2.4 KB)
  __shared__ float Gs[256 * 24];     // G[bo] rows (24.6 KB)
  const int bo = blockIdx.x;         // 0..511
  const int t = threadIdx.x;         // 0..255
  const int l = t & 63, wq = t >> 6;

  for (int e = t; e < 128 * 13; e += 256) {
    int h = e / 13, j = e % 13;
    float s, c;
    sincosf(TPI * (float)((h * j) & 255) * (1.0f / 256.0f), &s, &c);
    tw[h * 27 + 2 * j] = c;
    tw[h * 27 + 2 * j + 1] = s;
  }
  if (t < 156) {
    int j = t / 12, kx = t % 12;
    const float2* F2 = reinterpret_cast<const float2*>(Ff);
    float lr = 0, li = 0, hr = 0, hi = 0;
    if (j < 12) { float2 v = F2[((size_t)j * 12 + kx) * 512 + bo]; lr = v.x; li = v.y; }
    if (j > 0)  { float2 v = F2[((size_t)(24 - j) * 12 + kx) * 512 + bo]; hr = v.x; hi = v.y; }
    PQ[(j * 12 + kx) * 4 + 0] = lr + hr;  // Pr
    PQ[(j * 12 + kx) * 4 + 1] = li + hi;  // Pi
    PQ[(j * 12 + kx) * 4 + 2] = hi - li;  // Qr
    PQ[(j * 12 + kx) * 4 + 3] = lr - hr;  // Qi
  }
  __syncthreads();

  // Phase A: inverse ky-DFT -> Gs (t < 192: 16 hq x 12 kx)
  if (t < 192) {
    const int kx = t % 12, hq = t / 12;  // hq 0..15
    float Pr[13], Pi[13], Qr[13], Qi[13];
#pragma unroll
    for (int j = 0; j < 13; j++) {
      Pr[j] = PQ[(j * 12 + kx) * 4 + 0];
      Pi[j] = PQ[(j * 12 + kx) * 4 + 1];
      Qr[j] = PQ[(j * 12 + kx) * 4 + 2];
      Qi[j] = PQ[(j * 12 + kx) * 4 + 3];
    }
    for (int hh = 0; hh < 8; hh++) {
      int h = hh * 16 + hq;  // 0..127
      float Er = 0, Ei = 0, Or = 0, Oi = 0;
#pragma unroll
      for (int j = 0; j < 13; j++) {
        float c = tw[h * 27 + 2 * j], s = tw[h * 27 + 2 * j + 1];
        if (j & 1) {
          Or = fmaf(Pr[j], c, Or); Or = fmaf(Qr[j], s, Or);
          Oi = fmaf(Pi[j], c, Oi); Oi = fmaf(Qi[j], s, Oi);
        } else {
          Er = fmaf(Pr[j], c, Er); Er = fmaf(Qr[j], s, Er);
          Ei = fmaf(Pi[j], c, Ei); Ei = fmaf(Qi[j], s, Ei);
        }
      }
      Gs[h * 24 + 2 * kx] = Er + Or;           // G[h]
      Gs[h * 24 + 2 * kx + 1] = Ei + Oi;
      Gs[(h + 128) * 24 + 2 * kx] = Er - Or;   // G[h+128]
      Gs[(h + 128) * 24 + 2 * kx + 1] = Ei - Oi;
    }
  }

  // Phase B twiddles (independent of Gs -> before barrier)
  float cA[12], sA[12], cB[12], sB[12];
#pragma unroll
  for (int kx = 1; kx < 12; kx++) {
    float s, c;
    __sincosf(TPI * (float)((kx * (2 * l)) & 255) * (1.0f / 256.0f), &s, &c);
    cA[kx] = c; sA[kx] = s;
    __sincosf(TPI * (float)((kx * (2 * l + 1)) & 255) * (1.0f / 256.0f), &s, &c);
    cB[kx] = c; sB[kx] = s;
  }
  __syncthreads();

  // Phase B: inverse w-DFT from Gs; NONTEMPORAL stores (don't evict x from L3)
  float* ob0 = out + ((size_t)bo * 256 + wq * 64) * 256;
  for (int rs = 0; rs < 64; rs++) {
    int rl = wq * 64 + rs;
    float g[24];
    const float4* gr4 = reinterpret_cast<const float4*>(&Gs[rl * 24]);
#pragma unroll
    for (int qq = 0; qq < 6; qq++) {
      float4 v = gr4[qq];
      g[4 * qq] = v.x; g[4 * qq + 1] = v.y; g[4 * qq + 2] = v.z; g[4 * qq + 3] = v.w;
    }
    float E0 = g[0], O0 = 0, E1 = g[0], O1 = 0;  // DC: Re(G0) only
#pragma unroll
    for (int kx = 1; kx < 12; kx++) {
      float ta = g[2 * kx] * cA[kx] - g[2 * kx + 1] * sA[kx];
      float tb = g[2 * kx] * cB[kx] - g[2 * kx + 1] * sB[kx];
      if (kx & 1) { O0 += ta; O1 += tb; } else { E0 += ta; E1 += tb; }
    }
    float* orow = ob0 + rs * 256;
    float2 v0 = make_float2(E0 + O0, E1 + O1);
    float2 v1 = make_float2(E0 - O0, E1 - O1);
    __builtin_nontemporal_store(*reinterpret_cast<double*>(&v0),
                                reinterpret_cast<double*>(&orow[2 * l]));
    __builtin_nontemporal_store(*reinterpret_cast<double*>(&v1),
                                reinterpret_cast<double*>(&orow[128 + 2 * l]));
  }
}

extern "C" void kernel_launch(void* const* d_in, const int* in_sizes, int n_in,
                              void* d_out, int out_size, void* d_ws, size_t ws_size,
                              hipStream_t stream) {
  const float* x = (const float*)d_in[0];
  const float* w1 = (const float*)d_in[1];
  const float* w2 = (const float*)d_in[2];
  float* out = (float*)d_out;
  float* ws = (float*)d_ws;

  float* Xf = ws;               // 2 x 294,912 floats (partial halves)
  float* Ff = ws + 589824;      //     294,912 floats

  k12_hwdft<<<1024, 256, 0, stream>>>(x, Xf);
  k3_mix<<<288, 256, 0, stream>>>(Xf, w1, w2, Ff);
  k45_inv<<<512, 256, 0, stream>>>(Ff, out);
}